// Round 6
// baseline (142.203 us; speedup 1.0000x reference)
//
#include <hip/hip_runtime.h>
#include <math.h>
#include <stdint.h>

typedef __attribute__((ext_vector_type(8))) __bf16 bf16x8;
typedef __attribute__((ext_vector_type(16))) float f32x16;

#define Z16 {0.f,0.f,0.f,0.f,0.f,0.f,0.f,0.f,0.f,0.f,0.f,0.f,0.f,0.f,0.f,0.f}

__device__ __forceinline__ unsigned short f2b(float f) {
  union { float f; uint32_t u; } v; v.f = f;
  uint32_t r = (v.u + 0x7FFFu + ((v.u >> 16) & 1u)) >> 16;
  return (unsigned short)r;
}
__device__ __forceinline__ float b2f(unsigned short u) {
  union { uint32_t u; float f; } v; v.u = ((uint32_t)u) << 16;
  return v.f;
}
__device__ __forceinline__ uint32_t pk2(float a, float b) {
  return (uint32_t)f2b(a) | ((uint32_t)f2b(b) << 16);
}
__device__ __forceinline__ uint32_t cvtpk(float lo, float hi) {
  uint32_t r;
  asm("v_cvt_pk_bf16_f32 %0, %1, %2" : "=v"(r) : "v"(lo), "v"(hi));
  return r;
}
__device__ __forceinline__ void glds16(const void* g, void* l) {
  __builtin_amdgcn_global_load_lds(
      (const __attribute__((address_space(1))) void*)g,
      (__attribute__((address_space(3))) void*)l, 16, 0, 0);
}
#define MFMA32(a, b, c) __builtin_amdgcn_mfma_f32_32x32x16_bf16(a, b, c, 0, 0, 0)

// ===================== fused preprocessing =====================
__global__ __launch_bounds__(256) void prep(
    const float* __restrict__ q, const float* __restrict__ x,
    unsigned short* __restrict__ qh, unsigned short* __restrict__ xh,
    const float* __restrict__ Wq, const float* __restrict__ Wk,
    const float* __restrict__ Wv, const float* __restrict__ Wo,
    const float* __restrict__ Wm, const float* __restrict__ We,
    unsigned short* __restrict__ WqT, unsigned short* __restrict__ WkvT,
    unsigned short* __restrict__ WoT, unsigned short* __restrict__ WmT,
    unsigned short* __restrict__ WeT,
    const float* __restrict__ bk, const float* __restrict__ bv,
    float* __restrict__ bkv) {
  __shared__ float T[64][68];
  const int bx = blockIdx.x, tid = threadIdx.x;
  if (bx < 2048) {
    const float* src = (bx < 1024) ? q : x;
    unsigned short* dst = (bx < 1024) ? qh : xh;
    const int i = (bx & 1023) * 256 + tid;
    float4 a = ((const float4*)src)[i * 2];
    float4 b = ((const float4*)src)[i * 2 + 1];
    uint4 o;
    o.x = pk2(a.x, a.y); o.y = pk2(a.z, a.w);
    o.z = pk2(b.x, b.y); o.w = pk2(b.z, b.w);
    ((uint4*)dst)[i] = o;
  } else if (bx < 2240) {
    int t = bx - 2048;
    const float* in; unsigned short* out; int ldin, ldout, kx, nx;
    if (t < 16)       { in = Wq; out = WqT;           ldin = 256;  ldout = 256;  kx = t & 3;  nx = t >> 2; }
    else if (t < 32)  { t -= 16;  in = Wk; out = WkvT;          ldin = 256;  ldout = 256;  kx = t & 3;  nx = t >> 2; }
    else if (t < 48)  { t -= 32;  in = Wv; out = WkvT + 65536;  ldin = 256;  ldout = 256;  kx = t & 3;  nx = t >> 2; }
    else if (t < 64)  { t -= 48;  in = Wo; out = WoT;           ldin = 256;  ldout = 256;  kx = t & 3;  nx = t >> 2; }
    else if (t < 128) { t -= 64;  in = Wm; out = WmT;           ldin = 1024; ldout = 256;  kx = t & 3;  nx = t >> 2; }
    else              { t -= 128; in = We; out = WeT;           ldin = 256;  ldout = 1024; kx = t & 15; nx = t >> 4; }
    const int k0 = kx * 64, n0 = nx * 64;
    const int r = tid >> 2, c16 = (tid & 3) * 16;
    #pragma unroll
    for (int i = 0; i < 4; ++i)
      *(float4*)&T[r][c16 + i * 4] =
          *(const float4*)&in[(size_t)(k0 + r) * ldin + n0 + c16 + i * 4];
    __syncthreads();
    const int n = tid >> 2, k16 = (tid & 3) * 16;
    uint32_t wb[8];
    #pragma unroll
    for (int p = 0; p < 8; ++p)
      wb[p] = pk2(T[k16 + 2 * p][n], T[k16 + 2 * p + 1][n]);
    uint4 o0, o1;
    o0.x = wb[0]; o0.y = wb[1]; o0.z = wb[2]; o0.w = wb[3];
    o1.x = wb[4]; o1.y = wb[5]; o1.z = wb[6]; o1.w = wb[7];
    *(uint4*)&out[(size_t)(n0 + n) * ldout + k0 + k16] = o0;
    *(uint4*)&out[(size_t)(n0 + n) * ldout + k0 + k16 + 8] = o1;
  } else {
    if (tid < 256) { bkv[tid] = bk[tid]; bkv[256 + tid] = bv[tid]; }
  }
}

// ===================== GEMM big: 128x64 tile, BK=64, dbuf 2-phase =====================
// EPI 6: KV projection; y<4 -> K normal to Cout(ldc), y>=4 -> V transposed to VtOut
__global__ __launch_bounds__(256, 2) void gemm_kv(
    const unsigned short* __restrict__ A, int lda,
    const unsigned short* __restrict__ Bt, int ldb,
    const float* __restrict__ bias,
    unsigned short* __restrict__ VtOut,
    void* __restrict__ Cout, int ldc, int K) {
  __shared__ __align__(16) unsigned short As[2 * 128 * 64];
  __shared__ __align__(16) unsigned short Bs[2 * 64 * 64];
  const int tid = threadIdx.x, lane = tid & 63, wid = tid >> 6;
  const int l31 = lane & 31, g2 = lane >> 5;
  const int m0 = blockIdx.x * 128, n0 = blockIdx.y * 64;

  const char* srcA[4];
  const char* srcB[2];
  #pragma unroll
  for (int p = 0; p < 4; ++p) {
    int row = p * 32 + wid * 8 + (lane >> 3);
    srcA[p] = (const char*)A + ((size_t)(m0 + row) * lda) * 2 + (lane & 7) * 16;
  }
  #pragma unroll
  for (int p = 0; p < 2; ++p) {
    int row = p * 32 + wid * 8 + (lane >> 3);
    srcB[p] = (const char*)Bt + ((size_t)(n0 + row) * ldb) * 2 + (lane & 7) * 16;
  }

  f32x16 acc0 = Z16, acc1 = Z16;
  const int nt = K >> 6;

  #pragma unroll
  for (int p = 0; p < 4; ++p) { glds16(srcA[p], &As[p * 2048 + wid * 512]); srcA[p] += 128; }
  #pragma unroll
  for (int p = 0; p < 2; ++p) { glds16(srcB[p], &Bs[p * 2048 + wid * 512]); srcB[p] += 128; }
  __syncthreads();

  for (int t = 0; t < nt; ++t) {
    const int cur = t & 1, nxt = cur ^ 1;
    if (t + 1 < nt) {
      #pragma unroll
      for (int p = 0; p < 4; ++p) { glds16(srcA[p], &As[nxt * 8192 + p * 2048 + wid * 512]); srcA[p] += 128; }
      #pragma unroll
      for (int p = 0; p < 2; ++p) { glds16(srcB[p], &Bs[nxt * 4096 + p * 2048 + wid * 512]); srcB[p] += 128; }
    }
    const char* as = (const char*)As + cur * 16384;
    const char* bs = (const char*)Bs + cur * 8192;
    #pragma unroll
    for (int kc = 0; kc < 4; ++kc) {
      const int xo = kc * 32 + g2 * 16;
      bf16x8 af  = *(const bf16x8*)(as + (wid * 32 + l31) * 128 + xo);
      bf16x8 b0v = *(const bf16x8*)(bs + l31 * 128 + xo);
      bf16x8 b1v = *(const bf16x8*)(bs + (32 + l31) * 128 + xo);
      acc0 = MFMA32(af, b0v, acc0);
      acc1 = MFMA32(af, b1v, acc1);
    }
    __syncthreads();
  }

  const int bb = m0 >> 11;          // batch (m0 multiple of 128)
  #pragma unroll
  for (int nb = 0; nb < 2; ++nb) {
    const f32x16& acc = nb ? acc1 : acc0;
    const int col = n0 + nb * 32 + l31;
    const float bs = bias[col];
    if (n0 < 256) {
      // K half: normal row-major bf16 store
      #pragma unroll
      for (int r = 0; r < 16; ++r) {
        const int m = m0 + wid * 32 + (r & 3) + 8 * (r >> 2) + 4 * g2;
        ((unsigned short*)Cout)[(size_t)m * ldc + col] = f2b(acc[r] + bs);
      }
    } else {
      // V half: transposed store Vt[(b*8+h)*32+d][k]
      const int hv = (col - 256) >> 5, dv = (col - 256) & 31;
      unsigned short* vrow = VtOut + ((size_t)(bb * 8 + hv) * 32 + dv) * 2048;
      #pragma unroll
      for (int tq = 0; tq < 4; ++tq) {
        const int ks = (m0 & 2047) + wid * 32 + 8 * tq + 4 * g2;
        uint2 wv;
        wv.x = pk2(acc[4 * tq + 0] + bs, acc[4 * tq + 1] + bs);
        wv.y = pk2(acc[4 * tq + 2] + bs, acc[4 * tq + 3] + bs);
        *(uint2*)(vrow + ks) = wv;
      }
    }
  }
}

// ===================== GEMM small: 64x64 tile, BK=64, dbuf 2-phase =====================
// EPI: 0 bias->bf16 | 1 bias,relu,+res->bf16 | 3 bias,+res->f32
template <int EPI>
__global__ __launch_bounds__(256, 2) void gemm_small(
    const unsigned short* __restrict__ A, int lda,
    const unsigned short* __restrict__ Bt, int ldb,
    const float* __restrict__ bias,
    const unsigned short* __restrict__ res, int ldr,
    void* __restrict__ Cout, int ldc, int K) {
  __shared__ __align__(16) unsigned short As[2 * 64 * 64];
  __shared__ __align__(16) unsigned short Bs[2 * 64 * 64];
  const int tid = threadIdx.x, lane = tid & 63, wid = tid >> 6;
  const int l31 = lane & 31, g2 = lane >> 5;
  const int m0 = blockIdx.x * 64, n0 = blockIdx.y * 64;
  const int wr = (wid >> 1) * 32, wc = (wid & 1) * 32;

  const char* srcA[2];
  const char* srcB[2];
  #pragma unroll
  for (int p = 0; p < 2; ++p) {
    int row = p * 32 + wid * 8 + (lane >> 3);
    srcA[p] = (const char*)A + ((size_t)(m0 + row) * lda) * 2 + (lane & 7) * 16;
    srcB[p] = (const char*)Bt + ((size_t)(n0 + row) * ldb) * 2 + (lane & 7) * 16;
  }

  f32x16 acc = Z16;
  const int nt = K >> 6;

  #pragma unroll
  for (int p = 0; p < 2; ++p) {
    glds16(srcA[p], &As[p * 2048 + wid * 512]); srcA[p] += 128;
    glds16(srcB[p], &Bs[p * 2048 + wid * 512]); srcB[p] += 128;
  }
  __syncthreads();

  for (int t = 0; t < nt; ++t) {
    const int cur = t & 1, nxt = cur ^ 1;
    if (t + 1 < nt) {
      #pragma unroll
      for (int p = 0; p < 2; ++p) {
        glds16(srcA[p], &As[nxt * 4096 + p * 2048 + wid * 512]); srcA[p] += 128;
        glds16(srcB[p], &Bs[nxt * 4096 + p * 2048 + wid * 512]); srcB[p] += 128;
      }
    }
    const char* as = (const char*)As + cur * 8192;
    const char* bs = (const char*)Bs + cur * 8192;
    #pragma unroll
    for (int kc = 0; kc < 4; ++kc) {
      const int xo = kc * 32 + g2 * 16;
      bf16x8 af = *(const bf16x8*)(as + (wr + l31) * 128 + xo);
      bf16x8 bf = *(const bf16x8*)(bs + (wc + l31) * 128 + xo);
      acc = MFMA32(af, bf, acc);
    }
    __syncthreads();
  }

  const int col = n0 + wc + l31;
  const float bs = bias[col];
  #pragma unroll
  for (int r = 0; r < 16; ++r) {
    const int m = m0 + wr + (r & 3) + 8 * (r >> 2) + 4 * g2;
    float v = acc[r] + bs;
    if (EPI == 1) v = fmaxf(v, 0.f);
    if (EPI == 1 || EPI == 3) v += b2f(res[(size_t)m * ldr + col]);
    if (EPI == 3)
      ((float*)Cout)[(size_t)m * ldc + col] = v;
    else
      ((unsigned short*)Cout)[(size_t)m * ldc + col] = f2b(v);
  }
}

// ===================== GEMM 128x128: BK=64, dbuf, bias+relu->bf16 =====================
__global__ __launch_bounds__(256, 2) void gemm_relu128(
    const unsigned short* __restrict__ A, int lda,
    const unsigned short* __restrict__ Bt, int ldb,
    const float* __restrict__ bias,
    unsigned short* __restrict__ Cout, int ldc, int K) {
  __shared__ __align__(16) unsigned short As[2 * 128 * 64];
  __shared__ __align__(16) unsigned short Bs[2 * 128 * 64];
  const int tid = threadIdx.x, lane = tid & 63, wid = tid >> 6;
  const int l31 = lane & 31, g2 = lane >> 5;
  const int m0 = blockIdx.x * 128, n0 = blockIdx.y * 128;
  const int wr = (wid >> 1) * 64, wc = (wid & 1) * 64;

  const char* srcA[4];
  const char* srcB[4];
  #pragma unroll
  for (int p = 0; p < 4; ++p) {
    int row = p * 32 + wid * 8 + (lane >> 3);
    srcA[p] = (const char*)A + ((size_t)(m0 + row) * lda) * 2 + (lane & 7) * 16;
    srcB[p] = (const char*)Bt + ((size_t)(n0 + row) * ldb) * 2 + (lane & 7) * 16;
  }

  f32x16 a00 = Z16, a01 = Z16, a10 = Z16, a11 = Z16;
  const int nt = K >> 6;

  #pragma unroll
  for (int p = 0; p < 4; ++p) {
    glds16(srcA[p], &As[p * 2048 + wid * 512]); srcA[p] += 128;
    glds16(srcB[p], &Bs[p * 2048 + wid * 512]); srcB[p] += 128;
  }
  __syncthreads();

  for (int t = 0; t < nt; ++t) {
    const int cur = t & 1, nxt = cur ^ 1;
    if (t + 1 < nt) {
      #pragma unroll
      for (int p = 0; p < 4; ++p) {
        glds16(srcA[p], &As[nxt * 8192 + p * 2048 + wid * 512]); srcA[p] += 128;
        glds16(srcB[p], &Bs[nxt * 8192 + p * 2048 + wid * 512]); srcB[p] += 128;
      }
    }
    const char* as = (const char*)As + cur * 16384;
    const char* bs = (const char*)Bs + cur * 16384;
    #pragma unroll
    for (int kc = 0; kc < 4; ++kc) {
      const int xo = kc * 32 + g2 * 16;
      bf16x8 af0 = *(const bf16x8*)(as + (wr + l31) * 128 + xo);
      bf16x8 af1 = *(const bf16x8*)(as + (wr + 32 + l31) * 128 + xo);
      bf16x8 bf0 = *(const bf16x8*)(bs + (wc + l31) * 128 + xo);
      bf16x8 bf1 = *(const bf16x8*)(bs + (wc + 32 + l31) * 128 + xo);
      a00 = MFMA32(af0, bf0, a00);
      a01 = MFMA32(af0, bf1, a01);
      a10 = MFMA32(af1, bf0, a10);
      a11 = MFMA32(af1, bf1, a11);
    }
    __syncthreads();
  }

  #pragma unroll
  for (int mf = 0; mf < 2; ++mf)
    #pragma unroll
    for (int nb = 0; nb < 2; ++nb) {
      const f32x16& acc = mf ? (nb ? a11 : a10) : (nb ? a01 : a00);
      const int col = n0 + wc + nb * 32 + l31;
      const float bs = bias[col];
      #pragma unroll
      for (int r = 0; r < 16; ++r) {
        const int m = m0 + wr + mf * 32 + (r & 3) + 8 * (r >> 2) + 4 * g2;
        Cout[(size_t)m * ldc + col] = f2b(fmaxf(acc[r] + bs, 0.f));
      }
    }
}

// ===================== attention v3: barrier-free, LDS-free =====================
// 512 blocks (XCD-swizzled), 4 independent waves; wave owns 32 q-rows.
// Fixed-max softmax: P = exp2(S'), normalize at end. K direct from Kb, V from Vt.
__global__ __launch_bounds__(256, 2) void attn3(
    const unsigned short* __restrict__ Qg,   // [8192][256]
    const unsigned short* __restrict__ Kb,   // [8192][256]
    const unsigned short* __restrict__ Vt,   // [(b*8+h)*32+d][2048]
    unsigned short* __restrict__ O1) {       // [8192][256]
  const int tid = threadIdx.x, lane = tid & 63, wid = tid >> 6;
  const int l31 = lane & 31, g2 = lane >> 5;
  const int w = (blockIdx.x >> 3) + (blockIdx.x & 7) * 64;
  const int b = w >> 7, h = (w >> 4) & 7, qt = w & 15;
  const int qrow = b * 2048 + qt * 128 + wid * 32 + l31;

  // Q B-fragments pre-scaled by 1/sqrt(32)*log2(e)
  const float SCL2 = 0.17677669529663687f * 1.4426950408889634f;
  bf16x8 qf0, qf1;
  {
    const unsigned short* qp = Qg + (size_t)qrow * 256 + h * 32 + g2 * 8;
    #pragma unroll
    for (int dc = 0; dc < 2; ++dc) {
      ushort4 r0 = *(const ushort4*)(qp + dc * 16);
      ushort4 r1 = *(const ushort4*)(qp + dc * 16 + 4);
      union { unsigned short s[8]; bf16x8 v; } u;
      u.s[0] = f2b(b2f(r0.x) * SCL2); u.s[1] = f2b(b2f(r0.y) * SCL2);
      u.s[2] = f2b(b2f(r0.z) * SCL2); u.s[3] = f2b(b2f(r0.w) * SCL2);
      u.s[4] = f2b(b2f(r1.x) * SCL2); u.s[5] = f2b(b2f(r1.y) * SCL2);
      u.s[6] = f2b(b2f(r1.z) * SCL2); u.s[7] = f2b(b2f(r1.w) * SCL2);
      if (dc == 0) qf0 = u.v; else qf1 = u.v;
    }
  }

  // per-lane fragment bases
  const char* kp = (const char*)(Kb + ((size_t)(b * 2048 + l31)) * 256 + h * 32 + g2 * 8);
  const char* vp = (const char*)(Vt + ((size_t)((b * 8 + h) * 32 + l31)) * 2048 + g2 * 8);

  union U { uint4 u; bf16x8 v; };
  U ck0, ck1, ck2, ck3, cv0, cv1, cv2, cv3;
  ck0.u = *(const uint4*)(kp + 0);
  ck1.u = *(const uint4*)(kp + 32);
  ck2.u = *(const uint4*)(kp + 32 * 512);
  ck3.u = *(const uint4*)(kp + 32 * 512 + 32);
  cv0.u = *(const uint4*)(vp + 0);
  cv1.u = *(const uint4*)(vp + 32);
  cv2.u = *(const uint4*)(vp + 64);
  cv3.u = *(const uint4*)(vp + 96);

  f32x16 oacc = Z16;
  float lr0 = 0.f, lr1 = 0.f;

  for (int kt = 0; kt < 2048; kt += 64) {
    const int ktn = (kt + 64) & 2047;  // wrap: last iter re-reads tile 0 (unused)
    U nk0, nk1, nk2, nk3, nv0, nv1, nv2, nv3;
    {
      const char* kq = kp + (size_t)ktn * 512;
      nk0.u = *(const uint4*)(kq + 0);
      nk1.u = *(const uint4*)(kq + 32);
      nk2.u = *(const uint4*)(kq + 32 * 512);
      nk3.u = *(const uint4*)(kq + 32 * 512 + 32);
      const char* vq = vp + (size_t)ktn * 2;
      nv0.u = *(const uint4*)(vq + 0);
      nv1.u = *(const uint4*)(vq + 32);
      nv2.u = *(const uint4*)(vq + 64);
      nv3.u = *(const uint4*)(vq + 96);
    }

    // S^T = K @ Q^T (log2 domain)
    f32x16 p0 = Z16, p1 = Z16;
    p0 = MFMA32(ck0.v, qf0, p0);
    p0 = MFMA32(ck1.v, qf1, p0);
    p1 = MFMA32(ck2.v, qf0, p1);
    p1 = MFMA32(ck3.v, qf1, p1);

    // P = exp2(S') ; accumulate per-lane denominator
    float s0 = 0.f, s1 = 0.f, s2 = 0.f, s3 = 0.f;
    #pragma unroll
    for (int i = 0; i < 16; i += 2) {
      p0[i]     = __builtin_amdgcn_exp2f(p0[i]);
      p0[i + 1] = __builtin_amdgcn_exp2f(p0[i + 1]);
      s0 += p0[i]; s1 += p0[i + 1];
    }
    #pragma unroll
    for (int i = 0; i < 16; i += 2) {
      p1[i]     = __builtin_amdgcn_exp2f(p1[i]);
      p1[i + 1] = __builtin_amdgcn_exp2f(p1[i + 1]);
      s2 += p1[i]; s3 += p1[i + 1];
    }
    lr0 += s0 + s1;
    lr1 += s2 + s3;

    // PV: O^T += V^T @ P^T (cvt_pk pack + xor32 regroup)
    #pragma unroll
    for (int rb = 0; rb < 2; ++rb) {
      const f32x16& pp = rb ? p1 : p0;
      #pragma unroll
      for (int c = 0; c < 2; ++c) {
        uint32_t A0 = cvtpk(pp[8 * c + 0], pp[8 * c + 1]);
        uint32_t A1 = cvtpk(pp[8 * c + 2], pp[8 * c + 3]);
        uint32_t B0 = cvtpk(pp[8 * c + 4], pp[8 * c + 5]);
        uint32_t B1 = cvtpk(pp[8 * c + 6], pp[8 * c + 7]);
        uint32_t pA0 = (uint32_t)__shfl_xor((int)A0, 32);
        uint32_t pB0 = (uint32_t)__shfl_xor((int)B0, 32);
        uint32_t pA1 = (uint32_t)__shfl_xor((int)A1, 32);
        uint32_t pB1 = (uint32_t)__shfl_xor((int)B1, 32);
        union { uint32_t u[4]; bf16x8 v; } fr;
        fr.u[0] = g2 ? pB0 : A0;
        fr.u[1] = g2 ? pB1 : A1;
        fr.u[2] = g2 ? B0 : pA0;
        fr.u[3] = g2 ? B1 : pA1;
        const U& vf = (rb == 0) ? (c == 0 ? cv0 : cv1) : (c == 0 ? cv2 : cv3);
        oacc = MFMA32(vf.v, fr.v, oacc);
      }
    }

    ck0 = nk0; ck1 = nk1; ck2 = nk2; ck3 = nk3;
    cv0 = nv0; cv1 = nv1; cv2 = nv2; cv3 = nv3;
  }

  // epilogue: O1 = Q + O^T / l
  float lrun = lr0 + lr1;
  lrun += __shfl_xor(lrun, 32);
  const float inv = 1.f / lrun;
  const unsigned short* qres = Qg + (size_t)qrow * 256 + h * 32;
  unsigned short* op = O1 + (size_t)qrow * 256 + h * 32;
  #pragma unroll
  for (int j = 0; j < 4; ++j) {
    const int d0 = 8 * j + 4 * g2;
    uint2 qv = *(const uint2*)(qres + d0);
    float r0 = b2f((unsigned short)(qv.x & 0xffff)) + oacc[4 * j + 0] * inv;
    float r1 = b2f((unsigned short)(qv.x >> 16))    + oacc[4 * j + 1] * inv;
    float r2 = b2f((unsigned short)(qv.y & 0xffff)) + oacc[4 * j + 2] * inv;
    float r3 = b2f((unsigned short)(qv.y >> 16))    + oacc[4 * j + 3] * inv;
    uint2 wv; wv.x = pk2(r0, r1); wv.y = pk2(r2, r3);
    *(uint2*)(op + d0) = wv;
  }
}

// ===================== LayerNorm (bf16 in/out) =====================
__global__ __launch_bounds__(256) void ln_k(
    const unsigned short* __restrict__ X, const float* __restrict__ gw,
    const float* __restrict__ bw, unsigned short* __restrict__ Y) {
  const int wid = threadIdx.x >> 6, lane = threadIdx.x & 63;
  const int row = blockIdx.x * 4 + wid;
  ushort4 xv = *(const ushort4*)(X + (size_t)row * 256 + lane * 4);
  float x0 = b2f(xv.x), x1 = b2f(xv.y), x2 = b2f(xv.z), x3 = b2f(xv.w);
  float s = x0 + x1 + x2 + x3;
  float sq = x0 * x0 + x1 * x1 + x2 * x2 + x3 * x3;
  #pragma unroll
  for (int off = 32; off >= 1; off >>= 1) {
    s += __shfl_xor(s, off);
    sq += __shfl_xor(sq, off);
  }
  const float mean = s * (1.f / 256.f);
  const float var = sq * (1.f / 256.f) - mean * mean;
  const float rstd = rsqrtf(var + 1e-5f);
  float4 gv = *(const float4*)&gw[lane * 4];
  float4 bv = *(const float4*)&bw[lane * 4];
  ushort4 o;
  o.x = f2b((x0 - mean) * rstd * gv.x + bv.x);
  o.y = f2b((x1 - mean) * rstd * gv.y + bv.y);
  o.z = f2b((x2 - mean) * rstd * gv.z + bv.z);
  o.w = f2b((x3 - mean) * rstd * gv.w + bv.w);
  *(ushort4*)(Y + (size_t)row * 256 + lane * 4) = o;
}

// ===================== launch =====================
extern "C" void kernel_launch(void* const* d_in, const int* in_sizes, int n_in,
                              void* d_out, int out_size, void* d_ws, size_t ws_size,
                              hipStream_t stream) {
  (void)in_sizes; (void)n_in; (void)out_size; (void)ws_size;
  const float* q = (const float*)d_in[0];
  const float* x = (const float*)d_in[1];
  const float* Wq = (const float*)d_in[2];
  const float* bq = (const float*)d_in[3];
  const float* Wk = (const float*)d_in[4];
  const float* bk = (const float*)d_in[5];
  const float* Wv = (const float*)d_in[6];
  const float* bv = (const float*)d_in[7];
  const float* Wo = (const float*)d_in[8];
  const float* bo = (const float*)d_in[9];
  const float* Wm = (const float*)d_in[10];
  const float* bm = (const float*)d_in[11];
  const float* We = (const float*)d_in[12];
  const float* be = (const float*)d_in[13];
  const float* g0 = (const float*)d_in[14];
  const float* b0 = (const float*)d_in[15];
  const float* g1 = (const float*)d_in[16];
  const float* b1 = (const float*)d_in[17];
  float* out = (float*)d_out;

  uint8_t* ws = (uint8_t*)d_ws;
  unsigned short* WqT  = (unsigned short*)(ws + 0);
  unsigned short* WkvT = (unsigned short*)(ws + 131072);
  unsigned short* WoT  = (unsigned short*)(ws + 393216);
  unsigned short* WmT  = (unsigned short*)(ws + 524288);
  unsigned short* WeT  = (unsigned short*)(ws + 1048576);
  float*          bkv  = (float*)(ws + 1572864);
  unsigned short* qh   = (unsigned short*)(ws + 1576960);   // 4 MB -> O1n
  unsigned short* xh   = (unsigned short*)(ws + 5771264);   // 4 MB -> O2
  unsigned short* Qb   = (unsigned short*)(ws + 9965568);   // 4 MB -> O2n
  unsigned short* Kb   = (unsigned short*)(ws + 14159872);  // 4 MB -> Mb
  unsigned short* Vt   = (unsigned short*)(ws + 18354176);  // 4 MB -> Mb
  unsigned short* O1   = (unsigned short*)(ws + 22548480);  // 4 MB -> Mb
  unsigned short* O1n  = qh;
  unsigned short* O2   = xh;
  unsigned short* O2n  = Qb;
  unsigned short* Mb   = Kb;  // 16 MB spanning Kb..O1+4MB (proven fits in ws)

  prep<<<2241, 256, 0, stream>>>(q, x, qh, xh, Wq, Wk, Wv, Wo, Wm, We,
                                 WqT, WkvT, WoT, WmT, WeT, bk, bv, bkv);

  // Q projection
  gemm_small<0><<<dim3(128, 4), 256, 0, stream>>>(qh, 256, WqT, 256, bq, nullptr, 0, Qb, 256, 256);
  // KV projection: K -> Kb[8192][256], V -> Vt transposed
  gemm_kv<<<dim3(64, 8), 256, 0, stream>>>(xh, 256, WkvT, 256, bkv, Vt, Kb, 256, 256);

  // attention + Q residual
  attn3<<<512, 256, 0, stream>>>(Qb, Kb, Vt, O1);

  // LN0
  ln_k<<<2048, 256, 0, stream>>>(O1, g0, b0, O1n);
  // O2 = O1n + relu(O1n @ Wo + bo)
  gemm_small<1><<<dim3(128, 4), 256, 0, stream>>>(O1n, 256, WoT, 256, bo, O1n, 256, O2, 256, 256);
  // LN1
  ln_k<<<2048, 256, 0, stream>>>(O2, g1, b1, O2n);

  // MLP: M = relu(O2n @ Wm + bm), 128x128 tile
  gemm_relu128<<<dim3(64, 8), 256, 0, stream>>>(O2n, 256, WmT, 256, bm, Mb, 1024, 256);
  // out = M @ We + be + O2 (fp32)
  gemm_small<3><<<dim3(128, 4), 256, 0, stream>>>(Mb, 1024, WeT, 1024, be, O2, 256, out, 256, 1024);
}

// Round 8
// 117.631 us; speedup vs baseline: 1.2089x; 1.2089x over previous
//
#include <hip/hip_runtime.h>
#include <math.h>
#include <stdint.h>

typedef __attribute__((ext_vector_type(8))) __bf16 bf16x8;
typedef __attribute__((ext_vector_type(16))) float f32x16;

#define Z16 {0.f,0.f,0.f,0.f,0.f,0.f,0.f,0.f,0.f,0.f,0.f,0.f,0.f,0.f,0.f,0.f}

__device__ __forceinline__ unsigned short f2b(float f) {
  union { float f; uint32_t u; } v; v.f = f;
  uint32_t r = (v.u + 0x7FFFu + ((v.u >> 16) & 1u)) >> 16;
  return (unsigned short)r;
}
__device__ __forceinline__ float b2f(unsigned short u) {
  union { uint32_t u; float f; } v; v.u = ((uint32_t)u) << 16;
  return v.f;
}
__device__ __forceinline__ uint32_t pk2(float a, float b) {
  return (uint32_t)f2b(a) | ((uint32_t)f2b(b) << 16);
}
__device__ __forceinline__ uint32_t cvtpk(float lo, float hi) {
  uint32_t r;
  asm("v_cvt_pk_bf16_f32 %0, %1, %2" : "=v"(r) : "v"(lo), "v"(hi));
  return r;
}
__device__ __forceinline__ void glds16(const void* g, void* l) {
  __builtin_amdgcn_global_load_lds(
      (const __attribute__((address_space(1))) void*)g,
      (__attribute__((address_space(3))) void*)l, 16, 0, 0);
}
#define MFMA32(a, b, c) __builtin_amdgcn_mfma_f32_32x32x16_bf16(a, b, c, 0, 0, 0)

// ===================== fused preprocessing =====================
__global__ __launch_bounds__(256) void prep(
    const float* __restrict__ q, const float* __restrict__ x,
    unsigned short* __restrict__ qh, unsigned short* __restrict__ xh,
    const float* __restrict__ Wq, const float* __restrict__ Wk,
    const float* __restrict__ Wv, const float* __restrict__ Wo,
    const float* __restrict__ Wm, const float* __restrict__ We,
    unsigned short* __restrict__ WqT, unsigned short* __restrict__ WkvT,
    unsigned short* __restrict__ WoT, unsigned short* __restrict__ WmT,
    unsigned short* __restrict__ WeT,
    const float* __restrict__ bk, const float* __restrict__ bv,
    float* __restrict__ bkv) {
  __shared__ float T[64][68];
  const int bx = blockIdx.x, tid = threadIdx.x;
  if (bx < 2048) {
    const float* src = (bx < 1024) ? q : x;
    unsigned short* dst = (bx < 1024) ? qh : xh;
    const int i = (bx & 1023) * 256 + tid;
    float4 a = ((const float4*)src)[i * 2];
    float4 b = ((const float4*)src)[i * 2 + 1];
    uint4 o;
    o.x = cvtpk(a.x, a.y); o.y = cvtpk(a.z, a.w);
    o.z = cvtpk(b.x, b.y); o.w = cvtpk(b.z, b.w);
    ((uint4*)dst)[i] = o;
  } else if (bx < 2240) {
    int t = bx - 2048;
    const float* in; unsigned short* out; int ldin, ldout, kx, nx;
    if (t < 16)       { in = Wq; out = WqT;           ldin = 256;  ldout = 256;  kx = t & 3;  nx = t >> 2; }
    else if (t < 32)  { t -= 16;  in = Wk; out = WkvT;          ldin = 256;  ldout = 256;  kx = t & 3;  nx = t >> 2; }
    else if (t < 48)  { t -= 32;  in = Wv; out = WkvT + 65536;  ldin = 256;  ldout = 256;  kx = t & 3;  nx = t >> 2; }
    else if (t < 64)  { t -= 48;  in = Wo; out = WoT;           ldin = 256;  ldout = 256;  kx = t & 3;  nx = t >> 2; }
    else if (t < 128) { t -= 64;  in = Wm; out = WmT;           ldin = 1024; ldout = 256;  kx = t & 3;  nx = t >> 2; }
    else              { t -= 128; in = We; out = WeT;           ldin = 256;  ldout = 1024; kx = t & 15; nx = t >> 4; }
    const int k0 = kx * 64, n0 = nx * 64;
    const int r = tid >> 2, c16 = (tid & 3) * 16;
    #pragma unroll
    for (int i = 0; i < 4; ++i)
      *(float4*)&T[r][c16 + i * 4] =
          *(const float4*)&in[(size_t)(k0 + r) * ldin + n0 + c16 + i * 4];
    __syncthreads();
    const int n = tid >> 2, k16 = (tid & 3) * 16;
    uint32_t wb[8];
    #pragma unroll
    for (int p = 0; p < 8; ++p)
      wb[p] = cvtpk(T[k16 + 2 * p][n], T[k16 + 2 * p + 1][n]);
    uint4 o0, o1;
    o0.x = wb[0]; o0.y = wb[1]; o0.z = wb[2]; o0.w = wb[3];
    o1.x = wb[4]; o1.y = wb[5]; o1.z = wb[6]; o1.w = wb[7];
    *(uint4*)&out[(size_t)(n0 + n) * ldout + k0 + k16] = o0;
    *(uint4*)&out[(size_t)(n0 + n) * ldout + k0 + k16 + 8] = o1;
  } else {
    if (tid < 256) { bkv[tid] = bk[tid]; bkv[256 + tid] = bv[tid]; }
  }
}

// ===================== GEMM KV: 128x64 tile, BK=64, dbuf; K normal + V transposed =====================
__global__ __launch_bounds__(256, 2) void gemm_kv(
    const unsigned short* __restrict__ A, int lda,
    const unsigned short* __restrict__ Bt, int ldb,
    const float* __restrict__ bias,
    unsigned short* __restrict__ VtOut,
    void* __restrict__ Cout, int ldc, int K) {
  __shared__ __align__(16) unsigned short As[2 * 128 * 64];
  __shared__ __align__(16) unsigned short Bs[2 * 64 * 64];
  const int tid = threadIdx.x, lane = tid & 63, wid = tid >> 6;
  const int l31 = lane & 31, g2 = lane >> 5;
  const int m0 = blockIdx.x * 128, n0 = blockIdx.y * 64;

  const char* srcA[4];
  const char* srcB[2];
  #pragma unroll
  for (int p = 0; p < 4; ++p) {
    int row = p * 32 + wid * 8 + (lane >> 3);
    srcA[p] = (const char*)A + ((size_t)(m0 + row) * lda) * 2 + (lane & 7) * 16;
  }
  #pragma unroll
  for (int p = 0; p < 2; ++p) {
    int row = p * 32 + wid * 8 + (lane >> 3);
    srcB[p] = (const char*)Bt + ((size_t)(n0 + row) * ldb) * 2 + (lane & 7) * 16;
  }

  f32x16 acc0 = Z16, acc1 = Z16;
  const int nt = K >> 6;

  #pragma unroll
  for (int p = 0; p < 4; ++p) { glds16(srcA[p], &As[p * 2048 + wid * 512]); srcA[p] += 128; }
  #pragma unroll
  for (int p = 0; p < 2; ++p) { glds16(srcB[p], &Bs[p * 2048 + wid * 512]); srcB[p] += 128; }
  __syncthreads();

  for (int t = 0; t < nt; ++t) {
    const int cur = t & 1, nxt = cur ^ 1;
    if (t + 1 < nt) {
      #pragma unroll
      for (int p = 0; p < 4; ++p) { glds16(srcA[p], &As[nxt * 8192 + p * 2048 + wid * 512]); srcA[p] += 128; }
      #pragma unroll
      for (int p = 0; p < 2; ++p) { glds16(srcB[p], &Bs[nxt * 4096 + p * 2048 + wid * 512]); srcB[p] += 128; }
    }
    const char* as = (const char*)As + cur * 16384;
    const char* bs = (const char*)Bs + cur * 8192;
    #pragma unroll
    for (int kc = 0; kc < 4; ++kc) {
      const int xo = kc * 32 + g2 * 16;
      bf16x8 af  = *(const bf16x8*)(as + (wid * 32 + l31) * 128 + xo);
      bf16x8 b0v = *(const bf16x8*)(bs + l31 * 128 + xo);
      bf16x8 b1v = *(const bf16x8*)(bs + (32 + l31) * 128 + xo);
      acc0 = MFMA32(af, b0v, acc0);
      acc1 = MFMA32(af, b1v, acc1);
    }
    __syncthreads();
  }

  const int bb = m0 >> 11;
  #pragma unroll
  for (int nb = 0; nb < 2; ++nb) {
    const f32x16& acc = nb ? acc1 : acc0;
    const int col = n0 + nb * 32 + l31;
    const float bs = bias[col];
    if (n0 < 256) {
      #pragma unroll
      for (int r = 0; r < 16; ++r) {
        const int m = m0 + wid * 32 + (r & 3) + 8 * (r >> 2) + 4 * g2;
        ((unsigned short*)Cout)[(size_t)m * ldc + col] = f2b(acc[r] + bs);
      }
    } else {
      const int hv = (col - 256) >> 5, dv = (col - 256) & 31;
      unsigned short* vrow = VtOut + ((size_t)(bb * 8 + hv) * 32 + dv) * 2048;
      #pragma unroll
      for (int tq = 0; tq < 4; ++tq) {
        const int ks = (m0 & 2047) + wid * 32 + 8 * tq + 4 * g2;
        uint2 wv;
        wv.x = pk2(acc[4 * tq + 0] + bs, acc[4 * tq + 1] + bs);
        wv.y = pk2(acc[4 * tq + 2] + bs, acc[4 * tq + 3] + bs);
        *(uint2*)(vrow + ks) = wv;
      }
    }
  }
}

// ===================== GEMM small: 64x64 tile, BK=64, dbuf =====================
// EPI: 0 bias->bf16 | 1 bias,relu,+res->bf16 | 3 bias,+res->f32
template <int EPI>
__global__ __launch_bounds__(256, 2) void gemm_small(
    const unsigned short* __restrict__ A, int lda,
    const unsigned short* __restrict__ Bt, int ldb,
    const float* __restrict__ bias,
    const unsigned short* __restrict__ res, int ldr,
    void* __restrict__ Cout, int ldc, int K) {
  __shared__ __align__(16) unsigned short As[2 * 64 * 64];
  __shared__ __align__(16) unsigned short Bs[2 * 64 * 64];
  const int tid = threadIdx.x, lane = tid & 63, wid = tid >> 6;
  const int l31 = lane & 31, g2 = lane >> 5;
  const int m0 = blockIdx.x * 64, n0 = blockIdx.y * 64;
  const int wr = (wid >> 1) * 32, wc = (wid & 1) * 32;

  const char* srcA[2];
  const char* srcB[2];
  #pragma unroll
  for (int p = 0; p < 2; ++p) {
    int row = p * 32 + wid * 8 + (lane >> 3);
    srcA[p] = (const char*)A + ((size_t)(m0 + row) * lda) * 2 + (lane & 7) * 16;
    srcB[p] = (const char*)Bt + ((size_t)(n0 + row) * ldb) * 2 + (lane & 7) * 16;
  }

  f32x16 acc = Z16;
  const int nt = K >> 6;

  #pragma unroll
  for (int p = 0; p < 2; ++p) {
    glds16(srcA[p], &As[p * 2048 + wid * 512]); srcA[p] += 128;
    glds16(srcB[p], &Bs[p * 2048 + wid * 512]); srcB[p] += 128;
  }
  __syncthreads();

  for (int t = 0; t < nt; ++t) {
    const int cur = t & 1, nxt = cur ^ 1;
    if (t + 1 < nt) {
      #pragma unroll
      for (int p = 0; p < 2; ++p) {
        glds16(srcA[p], &As[nxt * 4096 + p * 2048 + wid * 512]); srcA[p] += 128;
        glds16(srcB[p], &Bs[nxt * 4096 + p * 2048 + wid * 512]); srcB[p] += 128;
      }
    }
    const char* as = (const char*)As + cur * 8192;
    const char* bs = (const char*)Bs + cur * 8192;
    #pragma unroll
    for (int kc = 0; kc < 4; ++kc) {
      const int xo = kc * 32 + g2 * 16;
      bf16x8 af = *(const bf16x8*)(as + (wr + l31) * 128 + xo);
      bf16x8 bf = *(const bf16x8*)(bs + (wc + l31) * 128 + xo);
      acc = MFMA32(af, bf, acc);
    }
    __syncthreads();
  }

  const int col = n0 + wc + l31;
  const float bs = bias[col];
  #pragma unroll
  for (int r = 0; r < 16; ++r) {
    const int m = m0 + wr + (r & 3) + 8 * (r >> 2) + 4 * g2;
    float v = acc[r] + bs;
    if (EPI == 1) v = fmaxf(v, 0.f);
    if (EPI == 1 || EPI == 3) v += b2f(res[(size_t)m * ldr + col]);
    if (EPI == 3)
      ((float*)Cout)[(size_t)m * ldc + col] = v;
    else
      ((unsigned short*)Cout)[(size_t)m * ldc + col] = f2b(v);
  }
}

// ===================== GEMM 128x128: BK=64, dbuf, bias+relu->bf16 =====================
__global__ __launch_bounds__(256, 2) void gemm_relu128(
    const unsigned short* __restrict__ A, int lda,
    const unsigned short* __restrict__ Bt, int ldb,
    const float* __restrict__ bias,
    unsigned short* __restrict__ Cout, int ldc, int K) {
  __shared__ __align__(16) unsigned short As[2 * 128 * 64];
  __shared__ __align__(16) unsigned short Bs[2 * 128 * 64];
  const int tid = threadIdx.x, lane = tid & 63, wid = tid >> 6;
  const int l31 = lane & 31, g2 = lane >> 5;
  const int m0 = blockIdx.x * 128, n0 = blockIdx.y * 128;
  const int wr = (wid >> 1) * 64, wc = (wid & 1) * 64;

  const char* srcA[4];
  const char* srcB[4];
  #pragma unroll
  for (int p = 0; p < 4; ++p) {
    int row = p * 32 + wid * 8 + (lane >> 3);
    srcA[p] = (const char*)A + ((size_t)(m0 + row) * lda) * 2 + (lane & 7) * 16;
    srcB[p] = (const char*)Bt + ((size_t)(n0 + row) * ldb) * 2 + (lane & 7) * 16;
  }

  f32x16 a00 = Z16, a01 = Z16, a10 = Z16, a11 = Z16;
  const int nt = K >> 6;

  #pragma unroll
  for (int p = 0; p < 4; ++p) {
    glds16(srcA[p], &As[p * 2048 + wid * 512]); srcA[p] += 128;
    glds16(srcB[p], &Bs[p * 2048 + wid * 512]); srcB[p] += 128;
  }
  __syncthreads();

  for (int t = 0; t < nt; ++t) {
    const int cur = t & 1, nxt = cur ^ 1;
    if (t + 1 < nt) {
      #pragma unroll
      for (int p = 0; p < 4; ++p) {
        glds16(srcA[p], &As[nxt * 8192 + p * 2048 + wid * 512]); srcA[p] += 128;
        glds16(srcB[p], &Bs[nxt * 8192 + p * 2048 + wid * 512]); srcB[p] += 128;
      }
    }
    const char* as = (const char*)As + cur * 16384;
    const char* bs = (const char*)Bs + cur * 16384;
    #pragma unroll
    for (int kc = 0; kc < 4; ++kc) {
      const int xo = kc * 32 + g2 * 16;
      bf16x8 af0 = *(const bf16x8*)(as + (wr + l31) * 128 + xo);
      bf16x8 af1 = *(const bf16x8*)(as + (wr + 32 + l31) * 128 + xo);
      bf16x8 bf0 = *(const bf16x8*)(bs + (wc + l31) * 128 + xo);
      bf16x8 bf1 = *(const bf16x8*)(bs + (wc + 32 + l31) * 128 + xo);
      a00 = MFMA32(af0, bf0, a00);
      a01 = MFMA32(af0, bf1, a01);
      a10 = MFMA32(af1, bf0, a10);
      a11 = MFMA32(af1, bf1, a11);
    }
    __syncthreads();
  }

  #pragma unroll
  for (int mf = 0; mf < 2; ++mf)
    #pragma unroll
    for (int nb = 0; nb < 2; ++nb) {
      const f32x16& acc = mf ? (nb ? a11 : a10) : (nb ? a01 : a00);
      const int col = n0 + wc + nb * 32 + l31;
      const float bs = bias[col];
      #pragma unroll
      for (int r = 0; r < 16; ++r) {
        const int m = m0 + wr + mf * 32 + (r & 3) + 8 * (r >> 2) + 4 * g2;
        Cout[(size_t)m * ldc + col] = f2b(fmaxf(acc[r] + bs, 0.f));
      }
    }
}

// ===================== attention v4: kv-split flash, no-max softmax =====================
// 1024 blocks (XCD-swizzled), 4 waves, wave owns 32 q-rows; each block does 1024 keys.
// Writes unnormalized O^T partials (f32) + per-row denominator (bf16).
#define KLD 40
#define VLD 72
__global__ __launch_bounds__(256, 4) void attn4(
    const unsigned short* __restrict__ Qg,   // [8192][256]
    const unsigned short* __restrict__ Kb,   // [8192][256]
    const unsigned short* __restrict__ Vt,   // [(b*8+h)*32+d][2048]
    float* __restrict__ Op0, float* __restrict__ Op1,
    unsigned short* __restrict__ lp) {       // bf16 [2][4][8][2048]
  __shared__ __align__(16) unsigned short Ks[64 * KLD];
  __shared__ __align__(16) unsigned short Vs[32 * VLD];
  const int tid = threadIdx.x, lane = tid & 63, wid = tid >> 6;
  const int l31 = lane & 31, g2 = lane >> 5;
  // swizzle: 128 consecutive work ids per XCD -> each (b,h,kv) 16-block group co-XCD
  const int w = (blockIdx.x >> 3) + (blockIdx.x & 7) * 128;
  const int b = w >> 8, h = (w >> 5) & 7, kv = (w >> 4) & 1, qt = w & 15;
  const int row0 = b * 2048 + qt * 128;
  const int qrow = row0 + wid * 32 + l31;
  const int kt0 = kv * 1024;

  // Q B-fragments pre-scaled by 1/sqrt(32)*log2(e)
  const float SCL2 = 0.17677669529663687f * 1.4426950408889634f;
  bf16x8 qf0, qf1;
  {
    const unsigned short* qp = Qg + (size_t)qrow * 256 + h * 32 + g2 * 8;
    #pragma unroll
    for (int dc = 0; dc < 2; ++dc) {
      ushort4 r0 = *(const ushort4*)(qp + dc * 16);
      ushort4 r1 = *(const ushort4*)(qp + dc * 16 + 4);
      union { unsigned short s[8]; bf16x8 v; } u;
      u.s[0] = f2b(b2f(r0.x) * SCL2); u.s[1] = f2b(b2f(r0.y) * SCL2);
      u.s[2] = f2b(b2f(r0.z) * SCL2); u.s[3] = f2b(b2f(r0.w) * SCL2);
      u.s[4] = f2b(b2f(r1.x) * SCL2); u.s[5] = f2b(b2f(r1.y) * SCL2);
      u.s[6] = f2b(b2f(r1.z) * SCL2); u.s[7] = f2b(b2f(r1.w) * SCL2);
      if (dc == 0) qf0 = u.v; else qf1 = u.v;
    }
  }

  // staging (coalesced): K rows, V from pre-transposed Vt
  const int ksr = tid >> 2, ksc = (tid & 3) * 8;
  const unsigned short* srcK = Kb + (size_t)(b * 2048 + kt0 + ksr) * 256 + h * 32 + ksc;
  const int vd = tid >> 3, vk = (tid & 7) * 8;
  const unsigned short* srcV = Vt + ((size_t)((b * 8 + h) * 32 + vd)) * 2048 + kt0 + vk;

  uint4 kreg = *(const uint4*)srcK;
  uint4 vreg = *(const uint4*)srcV;

  f32x16 oacc = Z16;
  float lr0 = 0.f, lr1 = 0.f;

  for (int kt = 0; kt < 1024; kt += 64) {
    *(uint4*)&Ks[ksr * KLD + ksc] = kreg;
    *(uint4*)&Vs[vd * VLD + vk] = vreg;
    __syncthreads();  // staged tile visible

    if (kt + 64 < 1024) {
      srcK += 64 * 256;
      kreg = *(const uint4*)srcK;
      srcV += 64;
      vreg = *(const uint4*)srcV;
    }

    // S^T = K @ Q^T (log2 domain)
    f32x16 p0 = Z16, p1 = Z16;
    {
      bf16x8 k00 = *(const bf16x8*)&Ks[l31 * KLD + g2 * 8];
      bf16x8 k01 = *(const bf16x8*)&Ks[l31 * KLD + 16 + g2 * 8];
      bf16x8 k10 = *(const bf16x8*)&Ks[(32 + l31) * KLD + g2 * 8];
      bf16x8 k11 = *(const bf16x8*)&Ks[(32 + l31) * KLD + 16 + g2 * 8];
      p0 = MFMA32(k00, qf0, p0);
      p0 = MFMA32(k01, qf1, p0);
      p1 = MFMA32(k10, qf0, p1);
      p1 = MFMA32(k11, qf1, p1);
    }

    // P = exp2(S'), accumulate denominator (no max tracking)
    float s0 = 0.f, s1 = 0.f;
    #pragma unroll
    for (int i = 0; i < 16; ++i) { p0[i] = __builtin_amdgcn_exp2f(p0[i]); s0 += p0[i]; }
    #pragma unroll
    for (int i = 0; i < 16; ++i) { p1[i] = __builtin_amdgcn_exp2f(p1[i]); s1 += p1[i]; }
    lr0 += s0; lr1 += s1;

    // PV: O^T += V^T @ P^T
    #pragma unroll
    for (int rb = 0; rb < 2; ++rb) {
      const f32x16& pp = rb ? p1 : p0;
      #pragma unroll
      for (int c = 0; c < 2; ++c) {
        uint32_t A0 = cvtpk(pp[8 * c + 0], pp[8 * c + 1]);
        uint32_t A1 = cvtpk(pp[8 * c + 2], pp[8 * c + 3]);
        uint32_t B0 = cvtpk(pp[8 * c + 4], pp[8 * c + 5]);
        uint32_t B1 = cvtpk(pp[8 * c + 6], pp[8 * c + 7]);
        uint32_t pA0 = (uint32_t)__shfl_xor((int)A0, 32);
        uint32_t pB0 = (uint32_t)__shfl_xor((int)B0, 32);
        uint32_t pA1 = (uint32_t)__shfl_xor((int)A1, 32);
        uint32_t pB1 = (uint32_t)__shfl_xor((int)B1, 32);
        union { uint32_t u[4]; bf16x8 v; } fr;
        fr.u[0] = g2 ? pB0 : A0;
        fr.u[1] = g2 ? pB1 : A1;
        fr.u[2] = g2 ? B0 : pA0;
        fr.u[3] = g2 ? B1 : pA1;
        bf16x8 vf = *(const bf16x8*)&Vs[l31 * VLD + rb * 32 + c * 16 + g2 * 8];
        oacc = MFMA32(vf, fr.v, oacc);
      }
    }
    __syncthreads();  // LDS reads done before next overwrite
  }

  // partial epilogue: unnormalized O^T (f32) + denominator
  float lrun = lr0 + lr1;
  lrun += __shfl_xor(lrun, 32);
  float* op = (kv ? Op1 : Op0) + (size_t)qrow * 256 + h * 32;
  #pragma unroll
  for (int j = 0; j < 4; ++j) {
    float4 v = make_float4(oacc[4 * j + 0], oacc[4 * j + 1],
                           oacc[4 * j + 2], oacc[4 * j + 3]);
    *(float4*)(op + 8 * j + 4 * g2) = v;
  }
  if (g2 == 0)
    lp[(((size_t)kv * 4 + b) * 8 + h) * 2048 + (qt * 128 + wid * 32 + l31)] = f2b(lrun);
}

// ===================== combine + Q residual + LN0 =====================
// one wave per row; O1n = LN0( Q + (Oa+Ob)/(la+lb) )
__global__ __launch_bounds__(256) void combine_ln0(
    const float* __restrict__ Op0, const float* __restrict__ Op1,
    const unsigned short* __restrict__ lp,
    const unsigned short* __restrict__ Qb,
    const float* __restrict__ gw, const float* __restrict__ bw,
    unsigned short* __restrict__ O1n) {
  const int wid = threadIdx.x >> 6, lane = threadIdx.x & 63;
  const int row = blockIdx.x * 4 + wid;
  const int b = row >> 11, rr = row & 2047, hh = lane >> 3;
  const float la = b2f(lp[(((size_t)0 * 4 + b) * 8 + hh) * 2048 + rr]);
  const float lb = b2f(lp[(((size_t)1 * 4 + b) * 8 + hh) * 2048 + rr]);
  const float inv = 1.f / (la + lb);
  float4 oa = *(const float4*)&Op0[(size_t)row * 256 + lane * 4];
  float4 ob = *(const float4*)&Op1[(size_t)row * 256 + lane * 4];
  ushort4 qv = *(const ushort4*)(Qb + (size_t)row * 256 + lane * 4);
  float x0 = b2f(qv.x) + (oa.x + ob.x) * inv;
  float x1 = b2f(qv.y) + (oa.y + ob.y) * inv;
  float x2 = b2f(qv.z) + (oa.z + ob.z) * inv;
  float x3 = b2f(qv.w) + (oa.w + ob.w) * inv;
  float s = x0 + x1 + x2 + x3;
  float sq = x0 * x0 + x1 * x1 + x2 * x2 + x3 * x3;
  #pragma unroll
  for (int off = 32; off >= 1; off >>= 1) {
    s += __shfl_xor(s, off);
    sq += __shfl_xor(sq, off);
  }
  const float mean = s * (1.f / 256.f);
  const float var = sq * (1.f / 256.f) - mean * mean;
  const float rstd = rsqrtf(var + 1e-5f);
  float4 gv = *(const float4*)&gw[lane * 4];
  float4 bv = *(const float4*)&bw[lane * 4];
  ushort4 o;
  o.x = f2b((x0 - mean) * rstd * gv.x + bv.x);
  o.y = f2b((x1 - mean) * rstd * gv.y + bv.y);
  o.z = f2b((x2 - mean) * rstd * gv.z + bv.z);
  o.w = f2b((x3 - mean) * rstd * gv.w + bv.w);
  *(ushort4*)(O1n + (size_t)row * 256 + lane * 4) = o;
}

// ===================== LayerNorm (bf16 in/out) =====================
__global__ __launch_bounds__(256) void ln_k(
    const unsigned short* __restrict__ X, const float* __restrict__ gw,
    const float* __restrict__ bw, unsigned short* __restrict__ Y) {
  const int wid = threadIdx.x >> 6, lane = threadIdx.x & 63;
  const int row = blockIdx.x * 4 + wid;
  ushort4 xv = *(const ushort4*)(X + (size_t)row * 256 + lane * 4);
  float x0 = b2f(xv.x), x1 = b2f(xv.y), x2 = b2f(xv.z), x3 = b2f(xv.w);
  float s = x0 + x1 + x2 + x3;
  float sq = x0 * x0 + x1 * x1 + x2 * x2 + x3 * x3;
  #pragma unroll
  for (int off = 32; off >= 1; off >>= 1) {
    s += __shfl_xor(s, off);
    sq += __shfl_xor(sq, off);
  }
  const float mean = s * (1.f / 256.f);
  const float var = sq * (1.f / 256.f) - mean * mean;
  const float rstd = rsqrtf(var + 1e-5f);
  float4 gv = *(const float4*)&gw[lane * 4];
  float4 bv = *(const float4*)&bw[lane * 4];
  ushort4 o;
  o.x = f2b((x0 - mean) * rstd * gv.x + bv.x);
  o.y = f2b((x1 - mean) * rstd * gv.y + bv.y);
  o.z = f2b((x2 - mean) * rstd * gv.z + bv.z);
  o.w = f2b((x3 - mean) * rstd * gv.w + bv.w);
  *(ushort4*)(Y + (size_t)row * 256 + lane * 4) = o;
}

// ===================== launch =====================
extern "C" void kernel_launch(void* const* d_in, const int* in_sizes, int n_in,
                              void* d_out, int out_size, void* d_ws, size_t ws_size,
                              hipStream_t stream) {
  (void)in_sizes; (void)n_in; (void)out_size; (void)ws_size;
  const float* q = (const float*)d_in[0];
  const float* x = (const float*)d_in[1];
  const float* Wq = (const float*)d_in[2];
  const float* bq = (const float*)d_in[3];
  const float* Wk = (const float*)d_in[4];
  const float* bk = (const float*)d_in[5];
  const float* Wv = (const float*)d_in[6];
  const float* bv = (const float*)d_in[7];
  const float* Wo = (const float*)d_in[8];
  const float* bo = (const float*)d_in[9];
  const float* Wm = (const float*)d_in[10];
  const float* bm = (const float*)d_in[11];
  const float* We = (const float*)d_in[12];
  const float* be = (const float*)d_in[13];
  const float* g0 = (const float*)d_in[14];
  const float* b0 = (const float*)d_in[15];
  const float* g1 = (const float*)d_in[16];
  const float* b1 = (const float*)d_in[17];
  float* out = (float*)d_out;

  uint8_t* ws = (uint8_t*)d_ws;
  // weights (prep outputs)
  unsigned short* WqT  = (unsigned short*)(ws + 0);        // dead after Qproj
  unsigned short* WkvT = (unsigned short*)(ws + 131072);   // dead after KVproj
  unsigned short* WoT  = (unsigned short*)(ws + 393216);
  unsigned short* WmT  = (unsigned short*)(ws + 524288);
  unsigned short* WeT  = (unsigned short*)(ws + 1048576);
  float*          bkv  = (float*)(ws + 1572864);
  // phase 1 activations
  unsigned short* qh   = (unsigned short*)(ws + 1576960);  // 4 MB, dead after Qproj
  unsigned short* xh   = (unsigned short*)(ws + 5771264);  // 4 MB, dead after KVproj
  unsigned short* Qb   = (unsigned short*)(ws + 9965568);  // 4 MB, live till combine
  unsigned short* Kb   = (unsigned short*)(ws + 14159872); // 4 MB, dead after attn
  unsigned short* Vt   = (unsigned short*)(ws + 18354176); // 4 MB, dead after attn
  // attention partials
  unsigned short* lpart = (unsigned short*)(ws + 0);       // 256 KB (over WqT/WkvT, dead)
  float* Op1 = (float*)(ws + 1576960);                     // 8 MB (over qh+xh, dead)
  float* Op0 = (float*)(ws + 22548480);                    // 8 MB (ends 30937088)
  // phase 2 reuse
  unsigned short* O1n = (unsigned short*)(ws + 14159872);  // over Kb (dead)
  unsigned short* O2  = (unsigned short*)(ws + 1576960);   // over Op1 (dead after combine)
  unsigned short* O2n = (unsigned short*)(ws + 5771264);
  unsigned short* Mb  = (unsigned short*)(ws + 14159872);  // 16 MB (O1n dead by then)

  prep<<<2241, 256, 0, stream>>>(q, x, qh, xh, Wq, Wk, Wv, Wo, Wm, We,
                                 WqT, WkvT, WoT, WmT, WeT, bk, bv, bkv);

  // Q projection
  gemm_small<0><<<dim3(128, 4), 256, 0, stream>>>(qh, 256, WqT, 256, bq, nullptr, 0, Qb, 256, 256);
  // KV projection: K -> Kb, V -> Vt transposed
  gemm_kv<<<dim3(64, 8), 256, 0, stream>>>(xh, 256, WkvT, 256, bkv, Vt, Kb, 256, 256);

  // attention (kv-split x2) -> partials
  attn4<<<1024, 256, 0, stream>>>(Qb, Kb, Vt, Op0, Op1, lpart);
  // combine + Q residual + LN0 -> O1n
  combine_ln0<<<2048, 256, 0, stream>>>(Op0, Op1, lpart, Qb, g0, b0, O1n);

  // O2 = O1n + relu(O1n @ Wo + bo)
  gemm_small<1><<<dim3(128, 4), 256, 0, stream>>>(O1n, 256, WoT, 256, bo, O1n, 256, O2, 256, 256);
  // LN1
  ln_k<<<2048, 256, 0, stream>>>(O2, g1, b1, O2n);

  // MLP: M = relu(O2n @ Wm + bm), 128x128 tile
  gemm_relu128<<<dim3(64, 8), 256, 0, stream>>>(O2n, 256, WmT, 256, bm, Mb, 1024, 256);
  // out = M @ We + be + O2 (fp32)
  gemm_small<3><<<dim3(128, 4), 256, 0, stream>>>(Mb, 1024, WeT, 1024, be, O2, 256, out, 256, 1024);
}